// Round 9
// baseline (120.605 us; speedup 1.0000x reference)
//
#include <hip/hip_runtime.h>
#include <hip/hip_bf16.h>

// TripletLoss batch-hard mining, B=8192, D=256.
// R10: R9 (symmetric tile-pair Gram, atomic-free slot combining) with the
//      occupancy fixed: __launch_bounds__(512,4) (128-reg cap, 2 blocks/CU)
//      made feasible by register trims: row labels packed 8-bit x4 into u32
//      (8 VGPR -> 2), int label compare (bit-identical key: fmaf(1,8,s)=8+s,
//      fmaf(0,8,s)=s), jt loop kept rolled. R9 showed cap-256 costs a
//      block/CU (1 resident, 3 rounds, 44 us); R8 showed cap-128 without
//      trims spills (44 MB scratch). This targets the gap.

constexpr int NB = 8192;
constexpr int ND = 256;
constexpr int TI = 256;               // rows per tile (8 waves x 32 rows)
constexpr int BJ = 64;                // cols staged per iteration
constexpr int NT = NB / TI;           // 32 tiles per side
constexpr int NPAIR = NT * (NT + 1) / 2;  // 528 blocks
constexpr int NITER = TI / BJ;        // 4

typedef __attribute__((ext_vector_type(8))) short bf16x8;
typedef __attribute__((ext_vector_type(4))) float f32x4;

typedef __attribute__((address_space(3))) unsigned int lds_u32;
typedef __attribute__((address_space(1))) const unsigned int g_u32;

__device__ inline void load_lds16(const unsigned short* g, unsigned short* l) {
    __builtin_amdgcn_global_load_lds((g_u32*)g, (lds_u32*)l, 16, 0, 0);
}

__device__ inline unsigned short f2bf(float v) {
    __hip_bfloat16 b = __float2bfloat16(v);
    return *reinterpret_cast<unsigned short*>(&b);
}

// ---------------- Kernel 1: normalize rows -> bf16, CHUNK-MAJOR ------------
// Register-resident; also inits accum/done. (posP/negP need NO init: every
// slot is written exactly once by mine_kernel.)
__global__ __launch_bounds__(256) void norm_kernel(const float* __restrict__ X,
                                                   unsigned short* __restrict__ Xbt,
                                                   float* accum, int* done) {
    const int t = threadIdx.x;
    const int rb = blockIdx.x * 32;
    const int r = t >> 3, e = t & 7;
    if (blockIdx.x == 0 && t == 0) { accum[0] = 0.f; accum[1] = 0.f; *done = 0; }

    const float4* src = (const float4*)(X + (size_t)(rb + r) * ND + e * 32);
    float4 v[8];
    #pragma unroll
    for (int k = 0; k < 8; k++) v[k] = src[k];

    float s = 0.f;
    #pragma unroll
    for (int k = 0; k < 8; k++) {
        s += v[k].x * v[k].x; s += v[k].y * v[k].y;
        s += v[k].z * v[k].z; s += v[k].w * v[k].w;
    }
    #pragma unroll
    for (int m = 1; m <= 4; m <<= 1) s += __shfl_xor(s, m, 64);
    const float sc = 1.0f / fmaxf(sqrtf(s), 1e-12f);

    #pragma unroll
    for (int k = 0; k < 4; k++) {
        const float* f = (const float*)&v[2 * k];
        unsigned short tmp[8];
        #pragma unroll
        for (int q = 0; q < 8; q++) tmp[q] = f2bf(f[q] * sc);
        *(bf16x8*)(Xbt + ((size_t)(e * 4 + k) * NB + rb + r) * 8) = *(bf16x8*)tmp;
    }
}

// ---------------- Kernel 2: symmetric Gram + two-direction hard mining ------
// Block = tile-pair (ti<=tj). 8 waves x 32 rows of ti in registers; 256 cols
// of tj staged in LDS 64 at a time. LDS region rg = kc*4+nf holds, at lane
// L*16B:  B[col = nf*16 + (L&15)][kchunk = kc*4 + (L>>4)] (lane-sequential).
// Mining key: key = s + 8*(lrow!=lcol); symmetric in (row,col).
// Partial-slot convention: contribution of partner tile u to index x lives at
// posP/negP[u*NB + x]. Row-dir -> slot tj. Col-dir -> slot ti. Each slot
// written once (diagonal: twice with bitwise-identical values - benign).
__global__ __launch_bounds__(512, 4) void mine_kernel(
    const unsigned short* __restrict__ Xbt, const int* __restrict__ labels,
    float* __restrict__ posP, float* __restrict__ negP) {
    __shared__ __align__(16) unsigned short Bt[32 * 512];  // 32 KB single buf
    __shared__ int Lall[TI];                               // tj's 256 labels
    __shared__ float colMn[8][BJ], colMx[8][BJ];           // per-wave col partials

    const int tid = threadIdx.x;
    const int w = tid >> 6;           // 0..7
    const int lane = tid & 63;
    const int quad = lane >> 4;
    const int l16 = lane & 15;

    // triangular decode: blockIdx.x -> (ti, tj), ti <= tj
    int ti = 0, rem = blockIdx.x;
    while (rem >= NT - ti) { rem -= NT - ti; ti++; }
    const int tj = ti + rem;

    const int rowbase = ti * TI + w * 32;
    const int jstart = tj * TI;

    if (tid < TI) Lall[tid] = labels[jstart + tid];

    // A fragments: afrag[rs][kc] = 16B of row (rowbase+rs*16+l16), chunk (kc*4+quad)
    bf16x8 afrag[2][8];
    #pragma unroll
    for (int rs = 0; rs < 2; rs++)
        #pragma unroll
        for (int kc = 0; kc < 8; kc++) {
            const size_t u = (size_t)(kc * 4 + quad) * NB + (rowbase + rs * 16 + l16);
            afrag[rs][kc] = *(const bf16x8*)(Xbt + u * 8);
        }

    // row labels packed 4x8-bit per rs (labels < 128 fit in a byte)
    unsigned int lpack[2];
    #pragma unroll
    for (int rs = 0; rs < 2; rs++) {
        unsigned int p = 0;
        #pragma unroll
        for (int r = 0; r < 4; r++)
            p |= ((unsigned int)labels[rowbase + rs * 16 + quad * 4 + r] & 0xffu)
                 << (8 * r);
        lpack[rs] = p;
    }

    float minK[2][4], maxK[2][4];
    #pragma unroll
    for (int rs = 0; rs < 2; rs++)
        #pragma unroll
        for (int r = 0; r < 4; r++) { minK[rs][r] = 1e30f; maxK[rs][r] = -1e30f; }

    auto stage = [&](int jt) {
        const int jbase = jstart + jt * BJ;
        #pragma unroll
        for (int s = 0; s < 4; s++) {
            const int rg = w * 4 + s;                 // 32 regions over 8 waves
            const int kc = rg >> 2, nfi = rg & 3;
            const size_t u = (size_t)(kc * 4 + quad) * NB + (jbase + nfi * 16 + l16);
            load_lds16(Xbt + u * 8, Bt + rg * 512);
        }
    };

    stage(0);
    __syncthreads();   // vmcnt drained: Bt(0) + Lall ready

    #pragma unroll 1
    for (int jt = 0; jt < NITER; jt++) {
        #pragma unroll
        for (int nf = 0; nf < 4; nf++) {
            const int flc = Lall[jt * BJ + nf * 16 + l16];
            f32x4 acc[2];
            #pragma unroll
            for (int rs = 0; rs < 2; rs++) acc[rs] = (f32x4){0.f, 0.f, 0.f, 0.f};
            #pragma unroll
            for (int kc = 0; kc < 8; kc++) {
                const bf16x8 b = *(const bf16x8*)(Bt + (kc * 4 + nf) * 512 + lane * 8);
                #pragma unroll
                for (int rs = 0; rs < 2; rs++)
                    acc[rs] = __builtin_amdgcn_mfma_f32_16x16x32_bf16(
                        afrag[rs][kc], b, acc[rs], 0, 0, 0);
            }
            float cP = 1e30f, cN = -1e30f;
            #pragma unroll
            for (int rs = 0; rs < 2; rs++)
                #pragma unroll
                for (int r = 0; r < 4; r++) {
                    const int lr = (int)((lpack[rs] >> (8 * r)) & 0xffu);
                    const float key = acc[rs][r] + ((lr != flc) ? 8.0f : 0.0f);
                    minK[rs][r] = fminf(minK[rs][r], key);   // row-direction
                    maxK[rs][r] = fmaxf(maxK[rs][r], key);
                    cP = fminf(cP, key);                     // col-direction
                    cN = fmaxf(cN, key);
                }
            // col-dir: combine the 4 quads (lanes sharing l16) -> min over 32 rows
            cP = fminf(cP, __shfl_xor(cP, 16, 64));
            cP = fminf(cP, __shfl_xor(cP, 32, 64));
            cN = fmaxf(cN, __shfl_xor(cN, 16, 64));
            cN = fmaxf(cN, __shfl_xor(cN, 32, 64));
            if (quad == 0) {
                colMn[w][nf * 16 + l16] = cP;
                colMx[w][nf * 16 + l16] = cN;
            }
        }
        __syncthreads();            // Bt reads + colMn/colMx writes done
        if (jt + 1 < NITER) stage(jt + 1);
        // flush col-direction partials for this jt: PLAIN stores, slot ti
        if (tid < BJ) {
            float m = colMn[0][tid];
            #pragma unroll
            for (int ww = 1; ww < 8; ww++) m = fminf(m, colMn[ww][tid]);
            posP[(size_t)ti * NB + jstart + jt * BJ + tid] = m;
        } else if (tid < 2 * BJ) {
            const int c = tid - BJ;
            float M = colMx[0][c];
            #pragma unroll
            for (int ww = 1; ww < 8; ww++) M = fmaxf(M, colMx[ww][c]);
            negP[(size_t)ti * NB + jstart + jt * BJ + c] = M;
        }
        __syncthreads();            // staged Bt landed (vmcnt 0)
    }

    // row-direction: reduce across the 16 lanes (bits 0..3) sharing each row;
    // PLAIN store into slot tj.
    #pragma unroll
    for (int rs = 0; rs < 2; rs++)
        #pragma unroll
        for (int r = 0; r < 4; r++) {
            float p = minK[rs][r], n = maxK[rs][r];
            #pragma unroll
            for (int m = 1; m <= 8; m <<= 1) {
                p = fminf(p, __shfl_xor(p, m, 64));
                n = fmaxf(n, __shfl_xor(n, m, 64));
            }
            if (l16 == 0) {
                const int row = rowbase + rs * 16 + quad * 4 + r;
                posP[(size_t)tj * NB + row] = p;
                negP[(size_t)tj * NB + row] = n;
            }
        }
}

// ---------------- Kernel 3: reduce 32 slots, hinge, finalize ----------------
__global__ __launch_bounds__(256) void finish_kernel(
    const float* __restrict__ posP, const float* __restrict__ negP,
    float* accum, int* done, float* __restrict__ out) {
    const int i = blockIdx.x * 256 + threadIdx.x;
    float p = 1e30f, n = -1e30f;
    #pragma unroll
    for (int u = 0; u < NT; u++) {
        p = fminf(p, posP[(size_t)u * NB + i]);
        n = fmaxf(n, negP[(size_t)u * NB + i]);
    }
    // p < 4: some positive existed; n > 4: some negative existed (key = s+8)
    const bool valid = (p < 4.0f) && (n > 4.0f);
    const float pos_d = fmaxf(1.0f - p, 0.0f);
    const float neg_d = fmaxf(1.0f - (n - 8.0f), 0.0f);
    float per = valid ? fmaxf(pos_d - neg_d + 1.0f, 0.0f) : 0.0f;
    float cnt = valid ? 1.0f : 0.0f;
    #pragma unroll
    for (int off = 32; off > 0; off >>= 1) {
        per += __shfl_down(per, off, 64);
        cnt += __shfl_down(cnt, off, 64);
    }
    __shared__ float sp[4], sc[4];
    const int wv = threadIdx.x >> 6, ln = threadIdx.x & 63;
    if (ln == 0) { sp[wv] = per; sc[wv] = cnt; }
    __syncthreads();
    if (threadIdx.x == 0) {
        atomicAdd(&accum[0], sp[0] + sp[1] + sp[2] + sp[3]);
        atomicAdd(&accum[1], sc[0] + sc[1] + sc[2] + sc[3]);
        __threadfence();
        const int old = atomicAdd(done, 1);
        if (old == (int)gridDim.x - 1) {
            const float s = __hip_atomic_load(&accum[0], __ATOMIC_RELAXED,
                                              __HIP_MEMORY_SCOPE_AGENT);
            const float c = __hip_atomic_load(&accum[1], __ATOMIC_RELAXED,
                                              __HIP_MEMORY_SCOPE_AGENT);
            out[0] = (c > 0.f) ? s / fmaxf(c, 1.f) : 0.f;
        }
    }
}

// ---------------- launcher --------------------------------------------------
extern "C" void kernel_launch(void* const* d_in, const int* in_sizes, int n_in,
                              void* d_out, int out_size, void* d_ws, size_t ws_size,
                              hipStream_t stream) {
    const float* X = (const float*)d_in[0];
    const int* labels = (const int*)d_in[1];
    float* out = (float*)d_out;

    char* ws = (char*)d_ws;
    unsigned short* Xbt = (unsigned short*)ws;                    // 4 MB
    float* posP = (float*)(ws + (size_t)4 * 1024 * 1024);         // 1 MB (32 x NB)
    float* negP = posP + (size_t)NT * NB;                         // 1 MB
    float* accum = negP + (size_t)NT * NB;                        // 8 B
    int* done = (int*)(accum + 2);                                // 4 B

    norm_kernel<<<NB / 32, 256, 0, stream>>>(X, Xbt, accum, done);
    mine_kernel<<<NPAIR, 512, 0, stream>>>(
        (const unsigned short*)Xbt, labels, posP, negP);
    finish_kernel<<<NB / 256, 256, 0, stream>>>(posP, negP, accum, done, out);
}

// Round 10
// 100.387 us; speedup vs baseline: 1.2014x; 1.2014x over previous
//
#include <hip/hip_runtime.h>
#include <hip/hip_bf16.h>

// TripletLoss batch-hard mining, B=8192, D=256.
// R11: symmetric tile-pair Gram with occupancy re-quantized. R9 showed
//      cap-256 + 512-thr blocks -> 2 waves/SIMD (1 block/CU, 3 rounds);
//      R8/R10 showed cap-128 spills (~150 regs live). Fix: 256-thr blocks
//      (4 waves, 1 wave/SIMD each) + __launch_bounds__(256,3) -> 170-reg
//      cap (headroom over ~150 demand) and 3 blocks/CU = 12 waves/CU.
//      TI=128 (4 waves x 32 rows), NT=64, NPAIR=2080 small blocks.
//      Per-wave structure (stage layout, MFMA order, int-label key,
//      atomic-free slot stores, diagonal benign race) unchanged from R10.

constexpr int NB = 8192;
constexpr int ND = 256;
constexpr int TI = 128;               // rows per tile (4 waves x 32 rows)
constexpr int BJ = 64;                // cols staged per iteration
constexpr int NT = NB / TI;           // 64 tiles per side
constexpr int NPAIR = NT * (NT + 1) / 2;  // 2080 blocks
constexpr int NITER = TI / BJ;        // 2

typedef __attribute__((ext_vector_type(8))) short bf16x8;
typedef __attribute__((ext_vector_type(4))) float f32x4;

typedef __attribute__((address_space(3))) unsigned int lds_u32;
typedef __attribute__((address_space(1))) const unsigned int g_u32;

__device__ inline void load_lds16(const unsigned short* g, unsigned short* l) {
    __builtin_amdgcn_global_load_lds((g_u32*)g, (lds_u32*)l, 16, 0, 0);
}

__device__ inline unsigned short f2bf(float v) {
    __hip_bfloat16 b = __float2bfloat16(v);
    return *reinterpret_cast<unsigned short*>(&b);
}

// ---------------- Kernel 1: normalize rows -> bf16, CHUNK-MAJOR ------------
// Register-resident; also inits accum/done. (posP/negP need NO init: every
// slot is written exactly once by mine_kernel.)
__global__ __launch_bounds__(256) void norm_kernel(const float* __restrict__ X,
                                                   unsigned short* __restrict__ Xbt,
                                                   float* accum, int* done) {
    const int t = threadIdx.x;
    const int rb = blockIdx.x * 32;
    const int r = t >> 3, e = t & 7;
    if (blockIdx.x == 0 && t == 0) { accum[0] = 0.f; accum[1] = 0.f; *done = 0; }

    const float4* src = (const float4*)(X + (size_t)(rb + r) * ND + e * 32);
    float4 v[8];
    #pragma unroll
    for (int k = 0; k < 8; k++) v[k] = src[k];

    float s = 0.f;
    #pragma unroll
    for (int k = 0; k < 8; k++) {
        s += v[k].x * v[k].x; s += v[k].y * v[k].y;
        s += v[k].z * v[k].z; s += v[k].w * v[k].w;
    }
    #pragma unroll
    for (int m = 1; m <= 4; m <<= 1) s += __shfl_xor(s, m, 64);
    const float sc = 1.0f / fmaxf(sqrtf(s), 1e-12f);

    #pragma unroll
    for (int k = 0; k < 4; k++) {
        const float* f = (const float*)&v[2 * k];
        unsigned short tmp[8];
        #pragma unroll
        for (int q = 0; q < 8; q++) tmp[q] = f2bf(f[q] * sc);
        *(bf16x8*)(Xbt + ((size_t)(e * 4 + k) * NB + rb + r) * 8) = *(bf16x8*)tmp;
    }
}

// ---------------- Kernel 2: symmetric Gram + two-direction hard mining ------
// Block = tile-pair (ti<=tj), 4 waves x 32 rows of ti in registers; 128 cols
// of tj staged in LDS 64 at a time. LDS region rg = kc*4+nf holds, at lane
// L*16B:  B[col = nf*16 + (L&15)][kchunk = kc*4 + (L>>4)] (lane-sequential).
// Mining key: key = s + 8*(lrow!=lcol); symmetric in (row,col).
// Slot convention: contribution of partner tile u to index x -> posP/negP
// [u*NB + x]. Row-dir -> slot tj. Col-dir -> slot ti. Each slot written once
// (diagonal: same slot written by both dirs with bitwise-identical values -
// min/max are order-independent - benign race, proven R8-R10).
__global__ __launch_bounds__(256, 3) void mine_kernel(
    const unsigned short* __restrict__ Xbt, const int* __restrict__ labels,
    float* __restrict__ posP, float* __restrict__ negP) {
    __shared__ __align__(16) unsigned short Bt[32 * 512];  // 32 KB single buf
    __shared__ int Lall[TI];                               // tj's 128 labels
    __shared__ float colMn[4][BJ], colMx[4][BJ];           // per-wave col partials

    const int tid = threadIdx.x;
    const int w = tid >> 6;           // 0..3
    const int lane = tid & 63;
    const int quad = lane >> 4;
    const int l16 = lane & 15;

    // triangular decode: blockIdx.x -> (ti, tj), ti <= tj
    int ti = 0, rem = blockIdx.x;
    while (rem >= NT - ti) { rem -= NT - ti; ti++; }
    const int tj = ti + rem;

    const int rowbase = ti * TI + w * 32;
    const int jstart = tj * TI;

    if (tid < TI) Lall[tid] = labels[jstart + tid];

    // A fragments: afrag[rs][kc] = 16B of row (rowbase+rs*16+l16), chunk (kc*4+quad)
    bf16x8 afrag[2][8];
    #pragma unroll
    for (int rs = 0; rs < 2; rs++)
        #pragma unroll
        for (int kc = 0; kc < 8; kc++) {
            const size_t u = (size_t)(kc * 4 + quad) * NB + (rowbase + rs * 16 + l16);
            afrag[rs][kc] = *(const bf16x8*)(Xbt + u * 8);
        }

    // row labels packed 4x8-bit per rs (labels < 128 fit in a byte)
    unsigned int lpack[2];
    #pragma unroll
    for (int rs = 0; rs < 2; rs++) {
        unsigned int p = 0;
        #pragma unroll
        for (int r = 0; r < 4; r++)
            p |= ((unsigned int)labels[rowbase + rs * 16 + quad * 4 + r] & 0xffu)
                 << (8 * r);
        lpack[rs] = p;
    }

    float minK[2][4], maxK[2][4];
    #pragma unroll
    for (int rs = 0; rs < 2; rs++)
        #pragma unroll
        for (int r = 0; r < 4; r++) { minK[rs][r] = 1e30f; maxK[rs][r] = -1e30f; }

    auto stage = [&](int jt) {
        const int jbase = jstart + jt * BJ;
        #pragma unroll
        for (int s = 0; s < 8; s++) {
            const int rg = w * 8 + s;                 // 32 regions over 4 waves
            const int kc = rg >> 2, nfi = rg & 3;
            const size_t u = (size_t)(kc * 4 + quad) * NB + (jbase + nfi * 16 + l16);
            load_lds16(Xbt + u * 8, Bt + rg * 512);
        }
    };

    stage(0);
    __syncthreads();   // vmcnt drained: Bt(0) + Lall ready

    #pragma unroll 1
    for (int jt = 0; jt < NITER; jt++) {
        #pragma unroll
        for (int nf = 0; nf < 4; nf++) {
            const int flc = Lall[jt * BJ + nf * 16 + l16];
            f32x4 acc[2];
            #pragma unroll
            for (int rs = 0; rs < 2; rs++) acc[rs] = (f32x4){0.f, 0.f, 0.f, 0.f};
            #pragma unroll
            for (int kc = 0; kc < 8; kc++) {
                const bf16x8 b = *(const bf16x8*)(Bt + (kc * 4 + nf) * 512 + lane * 8);
                #pragma unroll
                for (int rs = 0; rs < 2; rs++)
                    acc[rs] = __builtin_amdgcn_mfma_f32_16x16x32_bf16(
                        afrag[rs][kc], b, acc[rs], 0, 0, 0);
            }
            float cP = 1e30f, cN = -1e30f;
            #pragma unroll
            for (int rs = 0; rs < 2; rs++)
                #pragma unroll
                for (int r = 0; r < 4; r++) {
                    const int lr = (int)((lpack[rs] >> (8 * r)) & 0xffu);
                    const float key = acc[rs][r] + ((lr != flc) ? 8.0f : 0.0f);
                    minK[rs][r] = fminf(minK[rs][r], key);   // row-direction
                    maxK[rs][r] = fmaxf(maxK[rs][r], key);
                    cP = fminf(cP, key);                     // col-direction
                    cN = fmaxf(cN, key);
                }
            // col-dir: combine the 4 quads (lanes sharing l16) -> min over 32 rows
            cP = fminf(cP, __shfl_xor(cP, 16, 64));
            cP = fminf(cP, __shfl_xor(cP, 32, 64));
            cN = fmaxf(cN, __shfl_xor(cN, 16, 64));
            cN = fmaxf(cN, __shfl_xor(cN, 32, 64));
            if (quad == 0) {
                colMn[w][nf * 16 + l16] = cP;
                colMx[w][nf * 16 + l16] = cN;
            }
        }
        __syncthreads();            // Bt reads + colMn/colMx writes done
        if (jt + 1 < NITER) stage(jt + 1);
        // flush col-direction partials for this jt: PLAIN stores, slot ti
        if (tid < BJ) {
            float m = colMn[0][tid];
            #pragma unroll
            for (int ww = 1; ww < 4; ww++) m = fminf(m, colMn[ww][tid]);
            posP[(size_t)ti * NB + jstart + jt * BJ + tid] = m;
        } else if (tid < 2 * BJ) {
            const int c = tid - BJ;
            float M = colMx[0][c];
            #pragma unroll
            for (int ww = 1; ww < 4; ww++) M = fmaxf(M, colMx[ww][c]);
            negP[(size_t)ti * NB + jstart + jt * BJ + c] = M;
        }
        __syncthreads();            // staged Bt landed (vmcnt 0)
    }

    // row-direction: reduce across the 16 lanes (bits 0..3) sharing each row;
    // PLAIN store into slot tj.
    #pragma unroll
    for (int rs = 0; rs < 2; rs++)
        #pragma unroll
        for (int r = 0; r < 4; r++) {
            float p = minK[rs][r], n = maxK[rs][r];
            #pragma unroll
            for (int m = 1; m <= 8; m <<= 1) {
                p = fminf(p, __shfl_xor(p, m, 64));
                n = fmaxf(n, __shfl_xor(n, m, 64));
            }
            if (l16 == 0) {
                const int row = rowbase + rs * 16 + quad * 4 + r;
                posP[(size_t)tj * NB + row] = p;
                negP[(size_t)tj * NB + row] = n;
            }
        }
}

// ---------------- Kernel 3: reduce 64 slots, hinge, finalize ----------------
__global__ __launch_bounds__(256) void finish_kernel(
    const float* __restrict__ posP, const float* __restrict__ negP,
    float* accum, int* done, float* __restrict__ out) {
    const int i = blockIdx.x * 256 + threadIdx.x;
    float p = 1e30f, n = -1e30f;
    for (int u = 0; u < NT; u++) {
        p = fminf(p, posP[(size_t)u * NB + i]);
        n = fmaxf(n, negP[(size_t)u * NB + i]);
    }
    // p < 4: some positive existed; n > 4: some negative existed (key = s+8)
    const bool valid = (p < 4.0f) && (n > 4.0f);
    const float pos_d = fmaxf(1.0f - p, 0.0f);
    const float neg_d = fmaxf(1.0f - (n - 8.0f), 0.0f);
    float per = valid ? fmaxf(pos_d - neg_d + 1.0f, 0.0f) : 0.0f;
    float cnt = valid ? 1.0f : 0.0f;
    #pragma unroll
    for (int off = 32; off > 0; off >>= 1) {
        per += __shfl_down(per, off, 64);
        cnt += __shfl_down(cnt, off, 64);
    }
    __shared__ float sp[4], sc[4];
    const int wv = threadIdx.x >> 6, ln = threadIdx.x & 63;
    if (ln == 0) { sp[wv] = per; sc[wv] = cnt; }
    __syncthreads();
    if (threadIdx.x == 0) {
        atomicAdd(&accum[0], sp[0] + sp[1] + sp[2] + sp[3]);
        atomicAdd(&accum[1], sc[0] + sc[1] + sc[2] + sc[3]);
        __threadfence();
        const int old = atomicAdd(done, 1);
        if (old == (int)gridDim.x - 1) {
            const float s = __hip_atomic_load(&accum[0], __ATOMIC_RELAXED,
                                              __HIP_MEMORY_SCOPE_AGENT);
            const float c = __hip_atomic_load(&accum[1], __ATOMIC_RELAXED,
                                              __HIP_MEMORY_SCOPE_AGENT);
            out[0] = (c > 0.f) ? s / fmaxf(c, 1.f) : 0.f;
        }
    }
}

// ---------------- launcher --------------------------------------------------
extern "C" void kernel_launch(void* const* d_in, const int* in_sizes, int n_in,
                              void* d_out, int out_size, void* d_ws, size_t ws_size,
                              hipStream_t stream) {
    const float* X = (const float*)d_in[0];
    const int* labels = (const int*)d_in[1];
    float* out = (float*)d_out;

    char* ws = (char*)d_ws;
    unsigned short* Xbt = (unsigned short*)ws;                    // 4 MB
    float* posP = (float*)(ws + (size_t)4 * 1024 * 1024);         // 2 MB (64 x NB)
    float* negP = posP + (size_t)NT * NB;                         // 2 MB
    float* accum = negP + (size_t)NT * NB;                        // 8 B
    int* done = (int*)(accum + 2);                                // 4 B

    norm_kernel<<<NB / 32, 256, 0, stream>>>(X, Xbt, accum, done);
    mine_kernel<<<NPAIR, 256, 0, stream>>>(
        (const unsigned short*)Xbt, labels, posP, negP);
    finish_kernel<<<NB / 256, 256, 0, stream>>>(posP, negP, accum, done, out);
}